// Round 2
// baseline (866.936 us; speedup 1.0000x reference)
//
#include <hip/hip_runtime.h>
#include <stdint.h>

#define FEAT 512
#define HID  256
#define G1   512   // fused_main grid = number of partials (2 blocks/CU on 256 CUs)

typedef __attribute__((ext_vector_type(8))) short   short8;
typedef __attribute__((ext_vector_type(4))) float   floatx4;

__device__ inline unsigned short f2bf(float x){
  union { float f; uint32_t u; } v; v.f = x;
  uint32_t u = v.u;
  u += 0x7FFFu + ((u >> 16) & 1u);      // round-to-nearest-even
  return (unsigned short)(u >> 16);
}
__device__ inline float bf2f(unsigned short h){
  union { uint32_t u; float f; } v; v.u = ((uint32_t)h) << 16;
  return v.f;
}
__device__ inline float sigm_f(float x){ return 1.f/(1.f + __expf(-x)); }
__device__ inline float tanh_f(float x){ return 2.f/(1.f + __expf(-2.f*x)) - 1.f; }

__device__ inline short8 pack_bf8(float4 a, float4 b){
  union { short8 v; unsigned short u[8]; } r;
  r.u[0]=f2bf(a.x); r.u[1]=f2bf(a.y); r.u[2]=f2bf(a.z); r.u[3]=f2bf(a.w);
  r.u[4]=f2bf(b.x); r.u[5]=f2bf(b.y); r.u[6]=f2bf(b.z); r.u[7]=f2bf(b.w);
  return r.v;
}

// ---------------------------------------------------------------------------
// prep: W[K][256] fp32 row-major -> bf16 swizzled to MFMA B-fragment order:
// dst[((kb*16+nt)*64+lane)*8+j] = W[kb*32+(lane>>4)*8+j][nt*16+(lane&15)]
// ---------------------------------------------------------------------------
__global__ void prep_weights(const float* __restrict__ W1, const float* __restrict__ Wa,
                             const float* __restrict__ Wb,
                             unsigned short* __restrict__ W1bf,
                             unsigned short* __restrict__ Wabf,
                             unsigned short* __restrict__ Wbbf){
  int t = blockIdx.x*256 + threadIdx.x;
  const float* src; unsigned short* dst; int g;
  if      (t < 16384){ src = W1; dst = W1bf; g = t; }          // 16 kb * 16 nt * 64
  else if (t < 24576){ src = Wa; dst = Wabf; g = t - 16384; }  // 8 kb
  else if (t < 32768){ src = Wb; dst = Wbbf; g = t - 24576; }  // 8 kb
  else return;
  int lane = g & 63, nt = (g >> 6) & 15, kb = g >> 10;
  int col  = nt*16 + (lane & 15);
  int row0 = kb*32 + (lane >> 4)*8;
  unsigned short* d = dst + (size_t)g*8;
  const float*    s = src + (size_t)row0*HID + col;
  #pragma unroll
  for (int j = 0; j < 8; ++j) d[j] = f2bf(s[(size_t)j*HID]);
}

// ---------------------------------------------------------------------------
// Per-wave 32-token (or 16-token tail) tile, fully barrier-free.
// Weights read directly from pre-swizzled global (L1/L2-resident).
// ---------------------------------------------------------------------------
template<bool TWO>
__device__ __forceinline__ void do_tile(
    const float* __restrict__ x, int tok0,
    const unsigned short* __restrict__ W1bf,
    const unsigned short* __restrict__ Wabf,
    const unsigned short* __restrict__ Wbbf,
    const float* __restrict__ b1, const float* __restrict__ ba,
    const float* __restrict__ bb, const float* __restrict__ Wc, float bcv,
    float* __restrict__ s_buf,
    unsigned short (*__restrict__ hs)[264], float* __restrict__ pbufw,
    int lane, int quad, int l15,
    float& m_run, float& l_run, float& g0, float& g1, float& g2, float& g3)
{
  const short8* w1v = (const short8*)W1bf;
  const short8* wav = (const short8*)Wabf;
  const short8* wbv = (const short8*)Wbbf;

  // ---------------- GEMM1: h = relu(x @ W1 + b1), K=512 ----------------
  floatx4 acc0[16], acc1[16];
  #pragma unroll
  for (int nt = 0; nt < 16; ++nt){
    float bv = b1[nt*16 + l15];
    floatx4 t = {bv, bv, bv, bv};
    acc0[nt] = t;
    if (TWO) acc1[nt] = t;
  }
  const float* xr0 = x + (size_t)(tok0 + l15)*FEAT + quad*8;
  const float* xr1 = x + (size_t)(tok0 + 16 + l15)*FEAT + quad*8;

  // x pipeline: A = even-kb buffer, B = odd-kb buffer (1 kb-pair prefetch depth)
  float4 xA0[2], xB0[2], xA1[2], xB1[2];
  xA0[0] = *(const float4*)(xr0);       xA0[1] = *(const float4*)(xr0 + 4);
  xB0[0] = *(const float4*)(xr0 + 32);  xB0[1] = *(const float4*)(xr0 + 36);
  if (TWO){
    xA1[0] = *(const float4*)(xr1);       xA1[1] = *(const float4*)(xr1 + 4);
    xB1[0] = *(const float4*)(xr1 + 32);  xB1[1] = *(const float4*)(xr1 + 36);
  }
  #pragma unroll 1
  for (int i = 0; i < 8; ++i){
    const int kbe = 2*i, kbo = 2*i + 1;
    // even kb
    short8 af0 = pack_bf8(xA0[0], xA0[1]);
    short8 af1;
    if (TWO) af1 = pack_bf8(xA1[0], xA1[1]);
    if (i < 7){
      xA0[0] = *(const float4*)(xr0 + (kbe+2)*32);
      xA0[1] = *(const float4*)(xr0 + (kbe+2)*32 + 4);
      if (TWO){
        xA1[0] = *(const float4*)(xr1 + (kbe+2)*32);
        xA1[1] = *(const float4*)(xr1 + (kbe+2)*32 + 4);
      }
    }
    {
      const short8* wp = w1v + (size_t)kbe*1024 + lane;
      #pragma unroll
      for (int nt = 0; nt < 16; ++nt){
        short8 wf = wp[nt*64];
        acc0[nt] = __builtin_amdgcn_mfma_f32_16x16x32_bf16(af0, wf, acc0[nt], 0, 0, 0);
        if (TWO)
          acc1[nt] = __builtin_amdgcn_mfma_f32_16x16x32_bf16(af1, wf, acc1[nt], 0, 0, 0);
      }
    }
    // odd kb
    short8 bf0 = pack_bf8(xB0[0], xB0[1]);
    short8 bf1;
    if (TWO) bf1 = pack_bf8(xB1[0], xB1[1]);
    if (i < 7){
      xB0[0] = *(const float4*)(xr0 + (kbo+2)*32);
      xB0[1] = *(const float4*)(xr0 + (kbo+2)*32 + 4);
      if (TWO){
        xB1[0] = *(const float4*)(xr1 + (kbo+2)*32);
        xB1[1] = *(const float4*)(xr1 + (kbo+2)*32 + 4);
      }
    }
    {
      const short8* wp = w1v + (size_t)kbo*1024 + lane;
      #pragma unroll
      for (int nt = 0; nt < 16; ++nt){
        short8 wf = wp[nt*64];
        acc0[nt] = __builtin_amdgcn_mfma_f32_16x16x32_bf16(bf0, wf, acc0[nt], 0, 0, 0);
        if (TWO)
          acc1[nt] = __builtin_amdgcn_mfma_f32_16x16x32_bf16(bf1, wf, acc1[nt], 0, 0, 0);
      }
    }
  }
  // epilogue: relu, store bf16 h into this wave's private Hs strips
  #pragma unroll
  for (int nt = 0; nt < 16; ++nt){
    #pragma unroll
    for (int r = 0; r < 4; ++r){
      hs[quad*4 + r][nt*16 + l15] = f2bf(fmaxf(acc0[nt][r], 0.f));
      if (TWO) hs[16 + quad*4 + r][nt*16 + l15] = f2bf(fmaxf(acc1[nt][r], 0.f));
    }
  }

  // ---- GEMM2: a=tanh(h@Wa+ba), b=sigm(h@Wb+bb), s=(a*b)@Wc+bc, K=256 ----
  float s00=0.f,s01=0.f,s02=0.f,s03=0.f, s10=0.f,s11=0.f,s12=0.f,s13=0.f;
  #pragma unroll 1
  for (int nh = 0; nh < 2; ++nh){          // N-halves to cap register use
    floatx4 aa0[8], ab0[8], aa1[8], ab1[8];
    #pragma unroll
    for (int nt = 0; nt < 8; ++nt){
      int col = (nh*8 + nt)*16 + l15;
      float av = ba[col], bv = bb[col];
      floatx4 ta = {av, av, av, av};
      floatx4 tb = {bv, bv, bv, bv};
      aa0[nt] = ta; ab0[nt] = tb;
      if (TWO){ aa1[nt] = ta; ab1[nt] = tb; }
    }
    short8 hf0 = *(const short8*)&hs[l15][quad*8];
    short8 hf1;
    if (TWO) hf1 = *(const short8*)&hs[16 + l15][quad*8];
    #pragma unroll 1
    for (int kb = 0; kb < 8; ++kb){
      short8 cf0 = hf0, cf1;
      if (TWO) cf1 = hf1;
      if (kb < 7){
        hf0 = *(const short8*)&hs[l15][(kb+1)*32 + quad*8];
        if (TWO) hf1 = *(const short8*)&hs[16 + l15][(kb+1)*32 + quad*8];
      }
      const short8* wpa = wav + (size_t)(kb*16 + nh*8)*64 + lane;
      const short8* wpb = wbv + (size_t)(kb*16 + nh*8)*64 + lane;
      #pragma unroll
      for (int nt = 0; nt < 8; ++nt){
        short8 wfa = wpa[nt*64];
        short8 wfb = wpb[nt*64];
        aa0[nt] = __builtin_amdgcn_mfma_f32_16x16x32_bf16(cf0, wfa, aa0[nt], 0, 0, 0);
        ab0[nt] = __builtin_amdgcn_mfma_f32_16x16x32_bf16(cf0, wfb, ab0[nt], 0, 0, 0);
        if (TWO){
          aa1[nt] = __builtin_amdgcn_mfma_f32_16x16x32_bf16(cf1, wfa, aa1[nt], 0, 0, 0);
          ab1[nt] = __builtin_amdgcn_mfma_f32_16x16x32_bf16(cf1, wfb, ab1[nt], 0, 0, 0);
        }
      }
    }
    #pragma unroll
    for (int nt = 0; nt < 8; ++nt){
      float wcv = Wc[(nh*8 + nt)*16 + l15];
      s00 += tanh_f(aa0[nt][0]) * sigm_f(ab0[nt][0]) * wcv;
      s01 += tanh_f(aa0[nt][1]) * sigm_f(ab0[nt][1]) * wcv;
      s02 += tanh_f(aa0[nt][2]) * sigm_f(ab0[nt][2]) * wcv;
      s03 += tanh_f(aa0[nt][3]) * sigm_f(ab0[nt][3]) * wcv;
      if (TWO){
        s10 += tanh_f(aa1[nt][0]) * sigm_f(ab1[nt][0]) * wcv;
        s11 += tanh_f(aa1[nt][1]) * sigm_f(ab1[nt][1]) * wcv;
        s12 += tanh_f(aa1[nt][2]) * sigm_f(ab1[nt][2]) * wcv;
        s13 += tanh_f(aa1[nt][3]) * sigm_f(ab1[nt][3]) * wcv;
      }
    }
  }
  // reduce s across the 16 lanes of each l15-group (rows = quad*4+r)
  #pragma unroll
  for (int mk = 1; mk < 16; mk <<= 1){
    s00 += __shfl_xor(s00, mk, 64); s01 += __shfl_xor(s01, mk, 64);
    s02 += __shfl_xor(s02, mk, 64); s03 += __shfl_xor(s03, mk, 64);
    if (TWO){
      s10 += __shfl_xor(s10, mk, 64); s11 += __shfl_xor(s11, mk, 64);
      s12 += __shfl_xor(s12, mk, 64); s13 += __shfl_xor(s13, mk, 64);
    }
  }
  s00 += bcv; s01 += bcv; s02 += bcv; s03 += bcv;
  if (TWO){ s10 += bcv; s11 += bcv; s12 += bcv; s13 += bcv; }
  if (l15 == 0){
    float* sb = s_buf + tok0 + quad*4;
    sb[0] = s00; sb[1] = s01; sb[2] = s02; sb[3] = s03;
    if (TWO){
      float* sb1 = s_buf + tok0 + 16 + quad*4;
      sb1[0] = s10; sb1[1] = s11; sb1[2] = s12; sb1[3] = s13;
    }
  }
  // online softmax update (per wave)
  float tmax = fmaxf(fmaxf(s00, s01), fmaxf(s02, s03));
  if (TWO) tmax = fmaxf(tmax, fmaxf(fmaxf(s10, s11), fmaxf(s12, s13)));
  tmax = fmaxf(tmax, __shfl_xor(tmax, 16, 64));
  tmax = fmaxf(tmax, __shfl_xor(tmax, 32, 64));
  float m_new = fmaxf(m_run, tmax);
  float alpha = __expf(m_run - m_new);       // exp(-inf)=0 on first tile
  float p00 = __expf(s00 - m_new), p01 = __expf(s01 - m_new);
  float p02 = __expf(s02 - m_new), p03 = __expf(s03 - m_new);
  float psum = p00 + p01 + p02 + p03;
  float p10, p11, p12, p13;
  if (TWO){
    p10 = __expf(s10 - m_new); p11 = __expf(s11 - m_new);
    p12 = __expf(s12 - m_new); p13 = __expf(s13 - m_new);
    psum += p10 + p11 + p12 + p13;
  }
  psum += __shfl_xor(psum, 16, 64);
  psum += __shfl_xor(psum, 32, 64);          // sum over the 16 rows
  l_run = l_run*alpha + psum;
  m_run = m_new;
  if (l15 == 0){
    pbufw[quad*4+0] = p00; pbufw[quad*4+1] = p01;
    pbufw[quad*4+2] = p02; pbufw[quad*4+3] = p03;
    if (TWO){
      pbufw[16+quad*4+0] = p10; pbufw[16+quad*4+1] = p11;
      pbufw[16+quad*4+2] = p12; pbufw[16+quad*4+3] = p13;
    }
  }
  g0 *= alpha; g1 *= alpha; g2 *= alpha; g3 *= alpha;
  constexpr int NR = TWO ? 32 : 16;
  #pragma unroll
  for (int rw = 0; rw < NR; ++rw){
    float pr = pbufw[rw];
    const unsigned short* hp = &hs[rw][lane*4];
    g0 += pr*bf2f(hp[0]); g1 += pr*bf2f(hp[1]);
    g2 += pr*bf2f(hp[2]); g3 += pr*bf2f(hp[3]);
  }
}

// ---------------------------------------------------------------------------
// fused_main: barrier-free main loop. Each wave owns 32-token tiles (two
// 16-row MFMA strips sharing every weight fragment); 2048 waves x 3 tiles
// exactly cover 196608 tokens; 212-strip tail covers the rest.
// ---------------------------------------------------------------------------
__global__ __launch_bounds__(256, 2) void fused_main(
    const float* __restrict__ x,
    const float* __restrict__ b1, const float* __restrict__ ba,
    const float* __restrict__ bb, const float* __restrict__ Wc,
    const float* __restrict__ bc,
    const unsigned short* __restrict__ W1bf,
    const unsigned short* __restrict__ Wabf,
    const unsigned short* __restrict__ Wbbf,
    float* __restrict__ s_buf, float* __restrict__ partials, int ntok)
{
  __shared__ alignas(16) unsigned short Hs[4][32][264];  // per-wave h strips
  __shared__ float pbuf[4][32];

  const int tid  = threadIdx.x;
  const int wave = tid >> 6, lane = tid & 63;
  const int quad = lane >> 4, l15 = lane & 15;
  const int wid  = blockIdx.x*4 + wave;
  const int nw   = gridDim.x << 2;

  float m_run = -INFINITY, l_run = 0.f;
  float g0 = 0.f, g1 = 0.f, g2 = 0.f, g3 = 0.f;   // cols 4*lane .. 4*lane+3
  const float bcv = bc[0];

  const int nstrips  = ntok >> 4;              // 12500
  const int rounds   = (nstrips >> 1) / nw;    // 3
  const int tailbase = rounds * nw * 2;        // strip 12288
  const int ntail    = nstrips - tailbase;     // 212

  for (int r = 0; r < rounds; ++r){
    int tok0 = (r*nw + wid) * 32;
    do_tile<true>(x, tok0, W1bf, Wabf, Wbbf, b1, ba, bb, Wc, bcv,
                  s_buf, Hs[wave], pbuf[wave], lane, quad, l15,
                  m_run, l_run, g0, g1, g2, g3);
  }
  if (wid < ntail){
    int tok0 = (tailbase + wid) * 16;
    do_tile<false>(x, tok0, W1bf, Wabf, Wbbf, b1, ba, bb, Wc, bcv,
                   s_buf, Hs[wave], pbuf[wave], lane, quad, l15,
                   m_run, l_run, g0, g1, g2, g3);
  }

  // ---- combine 4 waves -> per-workgroup partial {M, L, g[256]} ----
  __syncthreads();
  float* fred = reinterpret_cast<float*>(&Hs[0][0][0]);   // reuse LDS
  if (lane == 0) fred[wave] = m_run;
  __syncthreads();
  float M = fmaxf(fmaxf(fred[0], fred[1]), fmaxf(fred[2], fred[3]));
  float sc = (m_run == -INFINITY) ? 0.f : __expf(m_run - M);
  if (lane == 0) fred[4 + wave] = l_run * sc;
  fred[8 + wave*256 + lane*4 + 0] = g0*sc;
  fred[8 + wave*256 + lane*4 + 1] = g1*sc;
  fred[8 + wave*256 + lane*4 + 2] = g2*sc;
  fred[8 + wave*256 + lane*4 + 3] = g3*sc;
  __syncthreads();
  float gsum = fred[8 + 0*256 + tid] + fred[8 + 1*256 + tid]
             + fred[8 + 2*256 + tid] + fred[8 + 3*256 + tid];
  float* P = partials + (size_t)blockIdx.x*258;
  if (tid == 0){ P[0] = M; P[1] = fred[4] + fred[5] + fred[6] + fred[7]; }
  P[2 + tid] = gsum;
}

// ---------------------------------------------------------------------------
// reduce_heads: combine G1 partials -> M, L, global_feat; then hr/cls/reg
// heads in exact fp32. 1024 threads, split-K parallel matvecs.
// ---------------------------------------------------------------------------
__global__ __launch_bounds__(1024) void reduce_heads(const float* __restrict__ partials,
    const float* __restrict__ Wr,   const float* __restrict__ br,
    const float* __restrict__ Wcls, const float* __restrict__ bcls,
    const float* __restrict__ Wreg, const float* __restrict__ breg,
    float* __restrict__ out, float* __restrict__ ML, int ntok)
{
  __shared__ float red[1024];
  __shared__ float scw[G1];
  __shared__ float gf[256];
  __shared__ float hr[256];
  const int t = threadIdx.x;

  // M = max over partials
  float lm = -INFINITY;
  for (int i = t; i < G1; i += 1024) lm = fmaxf(lm, partials[(size_t)i*258]);
  red[t] = lm; __syncthreads();
  for (int s = 512; s > 0; s >>= 1){ if (t < s) red[t] = fmaxf(red[t], red[t+s]); __syncthreads(); }
  float M = red[0];
  __syncthreads();

  // L and per-partial scale weights
  float ll = 0.f;
  for (int i = t; i < G1; i += 1024){
    float w = __expf(partials[(size_t)i*258] - M);
    scw[i] = w;
    ll += partials[(size_t)i*258 + 1] * w;
  }
  red[t] = ll; __syncthreads();
  for (int s = 512; s > 0; s >>= 1){ if (t < s) red[t] += red[t+s]; __syncthreads(); }
  float L = red[0];
  __syncthreads();

  // global_feat: 4 i-groups of 256 cols
  const int col = t & 255, grp = t >> 8;
  float g = 0.f;
  #pragma unroll 4
  for (int i = grp; i < G1; i += 4) g += partials[(size_t)i*258 + 2 + col] * scw[i];
  red[t] = g; __syncthreads();
  if (grp == 0){
    float gfv = (red[col] + red[256+col] + red[512+col] + red[768+col]) / L;
    gf[col] = gfv;
    out[ntok + col] = gfv;
    if (col == 0){ ML[0] = M; ML[1] = 1.f / L; }
  }
  __syncthreads();

  // hr = relu(gf @ Wr + br): split K into 4 parts of 64
  float h = 0.f;
  #pragma unroll 8
  for (int c = grp*64; c < grp*64 + 64; ++c) h += gf[c] * Wr[(size_t)c*256 + col];
  red[t] = h; __syncthreads();
  if (grp == 0){
    float hv = red[col] + red[256+col] + red[512+col] + red[768+col] + br[col];
    hr[col] = fmaxf(hv, 0.f);
  }
  __syncthreads();

  // heads: 8 lanes per output, strided K, shfl-reduce
  const int o = t >> 3, sl = t & 7;
  if (o < 33){
    float v = 0.f;
    #pragma unroll 8
    for (int j = sl; j < 256; j += 8) v += hr[j] * Wcls[(size_t)j*33 + o];
    v += __shfl_xor(v, 1, 64); v += __shfl_xor(v, 2, 64); v += __shfl_xor(v, 4, 64);
    if (sl == 0) out[ntok + 256 + o] = v + bcls[o];
  } else if (o >= 64 && o < 64 + 55){
    int oo = o - 64;
    float v = 0.f;
    #pragma unroll 8
    for (int j = sl; j < 256; j += 8) v += hr[j] * Wreg[(size_t)j*55 + oo];
    v += __shfl_xor(v, 1, 64); v += __shfl_xor(v, 2, 64); v += __shfl_xor(v, 4, 64);
    if (sl == 0) out[ntok + 289 + oo] = v + breg[oo];
  }
}

// ---------------------------------------------------------------------------
__global__ void finalize_A(const float* __restrict__ s_buf, const float* __restrict__ ML,
                           float* __restrict__ out, int ntok){
  int i = blockIdx.x*256 + threadIdx.x;
  if (i < ntok) out[i] = __expf(s_buf[i] - ML[0]) * ML[1];
}

// ---------------------------------------------------------------------------
extern "C" void kernel_launch(void* const* d_in, const int* in_sizes, int n_in,
                              void* d_out, int out_size, void* d_ws, size_t ws_size,
                              hipStream_t stream){
  (void)n_in; (void)out_size; (void)ws_size;
  const float* x    = (const float*)d_in[0];
  const float* W1   = (const float*)d_in[1];
  const float* b1   = (const float*)d_in[2];
  const float* Wa   = (const float*)d_in[3];
  const float* ba   = (const float*)d_in[4];
  const float* Wb   = (const float*)d_in[5];
  const float* bb   = (const float*)d_in[6];
  const float* Wc   = (const float*)d_in[7];
  const float* bc   = (const float*)d_in[8];
  const float* Wr   = (const float*)d_in[9];
  const float* br   = (const float*)d_in[10];
  const float* Wcls = (const float*)d_in[11];
  const float* bcls = (const float*)d_in[12];
  const float* Wreg = (const float*)d_in[13];
  const float* breg = (const float*)d_in[14];
  float* out = (float*)d_out;

  const int ntok = in_sizes[0] / FEAT;   // 200000

  char* ws = (char*)d_ws;
  float* s_buf = (float*)ws;
  size_t off = (size_t)ntok * 4;                                 // 800000
  float* partials = (float*)(ws + off); off += (size_t)G1*258*4; // +528384
  float* ML = (float*)(ws + off); off += 16;
  unsigned short* W1bf = (unsigned short*)(ws + off); off += (size_t)FEAT*HID*2;
  unsigned short* Wabf = (unsigned short*)(ws + off); off += (size_t)HID*HID*2;
  unsigned short* Wbbf = (unsigned short*)(ws + off); off += (size_t)HID*HID*2;
  // total ws use ~1.86 MB

  prep_weights<<<128, 256, 0, stream>>>(W1, Wa, Wb, W1bf, Wabf, Wbbf);
  fused_main<<<G1, 256, 0, stream>>>(x, b1, ba, bb, Wc, bc, W1bf, Wabf, Wbbf,
                                     s_buf, partials, ntok);
  reduce_heads<<<1, 1024, 0, stream>>>(partials, Wr, br, Wcls, bcls, Wreg, breg,
                                       out, ML, ntok);
  finalize_A<<<(ntok + 255)/256, 256, 0, stream>>>(s_buf, ML, out, ntok);
}